// Round 3
// baseline (1777.952 us; speedup 1.0000x reference)
//
#include <hip/hip_runtime.h>

#define EMB 128

__device__ inline float bf_lo(unsigned int u) { return __builtin_bit_cast(float, u << 16); }
__device__ inline float bf_hi(unsigned int u) { return __builtin_bit_cast(float, u & 0xffff0000u); }
__device__ inline float bf1(unsigned short u) { return __builtin_bit_cast(float, (unsigned int)u << 16); }
__device__ inline unsigned short f2bf(float x) {
    unsigned int u = __builtin_bit_cast(unsigned int, x);
    return (unsigned short)((u + 0x7fffu + ((u >> 16) & 1u)) >> 16);   // RNE
}

// ---------------- dtype probe: flag=1 if data is bf16-packed, 0 if fp32 ----------------
// fp32 N(0,1): exponent byte in [112,140] ~always. bf16 pairs reinterpreted as fp32:
// exponent field = low7(bf16 exp)<<1 | top mantissa bit -> lands in [112,140] ~never.
__global__ __launch_bounds__(256) void k_probe(const unsigned int* __restrict__ src,
                                               int* __restrict__ flag) {
    __shared__ int cnt;
    if (threadIdx.x == 0) cnt = 0;
    __syncthreads();
    unsigned int e = (src[threadIdx.x] >> 23) & 255u;
    if (e >= 112u && e <= 140u) atomicAdd(&cnt, 1);
    __syncthreads();
    if (threadIdx.x == 0) *flag = (cnt < 128) ? 1 : 0;
}

// ---------------- CSR build ----------------

__global__ void k_hist(const int* __restrict__ rows, int n, int* __restrict__ cnt) {
    for (int i = blockIdx.x * blockDim.x + threadIdx.x; i < n; i += gridDim.x * blockDim.x)
        atomicAdd(&cnt[rows[i]], 1);
}

__global__ __launch_bounds__(1024) void k_reduce(const int* __restrict__ cnt, int n,
                                                 int* __restrict__ bsum) {
    __shared__ int wsum[16];
    int tid = threadIdx.x;
    int idx = blockIdx.x * 1024 + tid;
    int v = (idx < n) ? cnt[idx] : 0;
    #pragma unroll
    for (int off = 32; off >= 1; off >>= 1) v += __shfl_down(v, off);
    if ((tid & 63) == 0) wsum[tid >> 6] = v;
    __syncthreads();
    if (tid == 0) {
        int s = 0;
        #pragma unroll
        for (int w = 0; w < 16; ++w) s += wsum[w];
        bsum[blockIdx.x] = s;
    }
}

__global__ __launch_bounds__(1024) void k_scan(const int* __restrict__ cnt, int n,
                                               int* __restrict__ ptr, int* __restrict__ cur) {
    __shared__ int wsum[16];
    __shared__ int wpre[16];
    __shared__ int s_carry;
    int tid = threadIdx.x, lane = tid & 63, wid = tid >> 6;
    if (tid == 0) s_carry = 0;
    __syncthreads();
    for (int base = 0; base < n; base += 1024) {
        int idx = base + tid;
        int v = (idx < n) ? cnt[idx] : 0;
        int incl = v;
        #pragma unroll
        for (int off = 1; off < 64; off <<= 1) {
            int t = __shfl_up(incl, off);
            if (lane >= off) incl += t;
        }
        if (lane == 63) wsum[wid] = incl;
        __syncthreads();
        if (tid == 0) {
            int run = s_carry;
            #pragma unroll
            for (int w = 0; w < 16; ++w) { wpre[w] = run; run += wsum[w]; }
            s_carry = run;
        }
        __syncthreads();
        int excl = wpre[wid] + incl - v;
        if (idx < n) { ptr[idx] = excl; cur[idx] = excl; }
        __syncthreads();
    }
    if (tid == 0) ptr[n] = s_carry;
}

__global__ __launch_bounds__(1024) void k_scan_apply(const int* __restrict__ cnt, int n,
                                                     const int* __restrict__ bpre,
                                                     int* __restrict__ ptr, int* __restrict__ cur,
                                                     int nb) {
    __shared__ int wsum[16];
    __shared__ int wpre[16];
    int tid = threadIdx.x, lane = tid & 63, wid = tid >> 6;
    int idx = blockIdx.x * 1024 + tid;
    int v = (idx < n) ? cnt[idx] : 0;
    int incl = v;
    #pragma unroll
    for (int off = 1; off < 64; off <<= 1) {
        int t = __shfl_up(incl, off);
        if (lane >= off) incl += t;
    }
    if (lane == 63) wsum[wid] = incl;
    __syncthreads();
    if (tid == 0) {
        int run = bpre[blockIdx.x];
        #pragma unroll
        for (int w = 0; w < 16; ++w) { wpre[w] = run; run += wsum[w]; }
    }
    __syncthreads();
    int excl = wpre[wid] + incl - v;
    if (idx < n) { ptr[idx] = excl; cur[idx] = excl; }
    if (idx == 0) ptr[n] = bpre[nb];
}

// entry = (col << 15) | (bf16 bits of val, sign=0 since vals in [0,1])
__global__ void k_scatter(const int* __restrict__ rows, const int* __restrict__ cols,
                          const void* __restrict__ vals, int n, const int* __restrict__ flag,
                          int* __restrict__ cur, unsigned int* __restrict__ ent) {
    int isbf = *flag;
    const unsigned short* v16 = (const unsigned short*)vals;
    const float* v32 = (const float*)vals;
    for (int i = blockIdx.x * blockDim.x + threadIdx.x; i < n; i += gridDim.x * blockDim.x) {
        int r = rows[i];
        int p = atomicAdd(&cur[r], 1);
        float v = isbf ? bf1(v16[i]) : v32[i];
        ent[p] = ((unsigned int)cols[i] << 15) | (unsigned int)f2bf(v);
    }
}

// ---------------- SpMM: one wave per output row; lane handles cols 2*lane, 2*lane+1 ----------------
// table dtype follows *flag; out dtype: out_follow ? *flag : forced bf16
__global__ __launch_bounds__(256) void k_spmm(const int* __restrict__ ptr,
                                              const unsigned int* __restrict__ ent,
                                              const void* __restrict__ table, size_t toff,
                                              void* __restrict__ out, int nrows,
                                              const int* __restrict__ flag, int out_follow) {
    int isbf = *flag;
    int outbf = out_follow ? isbf : 1;
    int lane = threadIdx.x & 63;
    int row = (blockIdx.x << 2) + (threadIdx.x >> 6);
    if (row >= nrows) return;
    const unsigned short* t16 = (const unsigned short*)table + toff;
    const float* t32 = (const float*)table + toff;
    int beg = ptr[row], end = ptr[row + 1];
    float a0 = 0.f, a1 = 0.f;
    for (int i = beg; i < end; i += 64) {
        int nb = min(64, end - i);
        unsigned int e = 0u;
        if (lane < nb) e = ent[i + lane];
        if (isbf) {
            #pragma unroll 4
            for (int j = 0; j < nb; ++j) {
                unsigned int ee = (unsigned int)__shfl((int)e, j);
                int c = (int)(ee >> 15);
                float v = __builtin_bit_cast(float, (ee & 0x7FFFu) << 16);
                unsigned int u = *(const unsigned int*)(t16 + ((size_t)c << 7) + (lane << 1));
                a0 = fmaf(v, bf_lo(u), a0);
                a1 = fmaf(v, bf_hi(u), a1);
            }
        } else {
            #pragma unroll 4
            for (int j = 0; j < nb; ++j) {
                unsigned int ee = (unsigned int)__shfl((int)e, j);
                int c = (int)(ee >> 15);
                float v = __builtin_bit_cast(float, (ee & 0x7FFFu) << 16);
                const float* fr = t32 + ((size_t)c << 7) + (lane << 1);
                a0 = fmaf(v, fr[0], a0);
                a1 = fmaf(v, fr[1], a1);
            }
        }
    }
    if (outbf) {
        unsigned int o = (unsigned int)f2bf(a0) | ((unsigned int)f2bf(a1) << 16);
        *(unsigned int*)((unsigned short*)out + ((size_t)row << 7) + (lane << 1)) = o;
    } else {
        float* po = (float*)out + ((size_t)row << 7) + (lane << 1);
        po[0] = a0;
        po[1] = a1;
    }
}

// ---------------- weight prep: wc[k][n] bf16 row-major, k<128: Wp@Wf_top, k>=128: We@Wf_bot ----------------
__global__ __launch_bounds__(128) void k_wprep(const void* __restrict__ Wp,
                                               const void* __restrict__ We,
                                               const void* __restrict__ Wf,
                                               const int* __restrict__ flag,
                                               unsigned short* __restrict__ wc) {
    int isbf = *flag;
    int k = blockIdx.x;    // 0..255
    int n = threadIdx.x;   // 0..127
    int src = (k < 128) ? k : (k - 128);
    int off = (k < 128) ? 0 : 128;
    const unsigned short* w16 = (const unsigned short*)((k < 128) ? Wp : We);
    const float* w32 = (const float*)((k < 128) ? Wp : We);
    const unsigned short* f16 = (const unsigned short*)Wf;
    const float* f32 = (const float*)Wf;
    float acc = 0.f;
    if (isbf) {
        #pragma unroll 4
        for (int j = 0; j < EMB; ++j)
            acc = fmaf(bf1(w16[(size_t)src * EMB + j]), bf1(f16[(size_t)(off + j) * EMB + n]), acc);
    } else {
        #pragma unroll 4
        for (int j = 0; j < EMB; ++j)
            acc = fmaf(w32[(size_t)src * EMB + j], f32[(size_t)(off + j) * EMB + n], acc);
    }
    wc[(size_t)k * EMB + n] = f2bf(acc);
}

// ---------------- fused GEMM (VALU, correctness-first): M=nrows, K=256, N=128 ----------------
// A row: k<128 from poi_agg (always bf16, parked at d_out base), k>=128 from edge (flag dtype).
// Block = 128 threads = 2 rows x 64 lanes; lane handles cols 2l, 2l+1.
__global__ __launch_bounds__(128) void k_fused(const unsigned short* __restrict__ poi_agg,
                                               const void* __restrict__ edge,
                                               void* __restrict__ d_out, size_t fused_off,
                                               int nrows, const int* __restrict__ flag,
                                               const unsigned short* __restrict__ wc) {
    __shared__ unsigned int lds_wc[16384];   // 64 KB: dword idx k*64+l = wc cols (2l,2l+1) at row k
    __shared__ float A_sh[2][256];
    int isbf = *flag;
    {
        const uint4* s = (const uint4*)wc;
        uint4* d = (uint4*)lds_wc;
        for (int i = threadIdx.x; i < 4096; i += 128) d[i] = s[i];
    }
    int r = threadIdx.x >> 6, l = threadIdx.x & 63;
    int row = blockIdx.x * 2 + r;
    const unsigned short* e16 = (const unsigned short*)edge;
    const float* e32 = (const float*)edge;
    if (row < nrows) {
        A_sh[r][l]       = bf1(poi_agg[(size_t)row * EMB + l]);
        A_sh[r][l + 64]  = bf1(poi_agg[(size_t)row * EMB + l + 64]);
        A_sh[r][l + 128] = isbf ? bf1(e16[(size_t)row * EMB + l])      : e32[(size_t)row * EMB + l];
        A_sh[r][l + 192] = isbf ? bf1(e16[(size_t)row * EMB + l + 64]) : e32[(size_t)row * EMB + l + 64];
    }
    __syncthreads();
    if (row >= nrows) return;
    float acc0 = 0.f, acc1 = 0.f;
    #pragma unroll 4
    for (int k = 0; k < 256; ++k) {
        float a = A_sh[r][k];
        unsigned int w = lds_wc[k * 64 + l];
        acc0 = fmaf(a, bf_lo(w), acc0);
        acc1 = fmaf(a, bf_hi(w), acc1);
    }
    size_t o = fused_off + (size_t)row * EMB + (l << 1);
    if (isbf) {
        unsigned int ov = (unsigned int)f2bf(acc0) | ((unsigned int)f2bf(acc1) << 16);
        *(unsigned int*)((unsigned short*)d_out + o) = ov;
    } else {
        float* po = (float*)d_out + o;
        po[0] = acc0;
        po[1] = acc1;
    }
}

extern "C" void kernel_launch(void* const* d_in, const int* in_sizes, int n_in,
                              void* d_out, int out_size, void* d_ws, size_t ws_size,
                              hipStream_t stream) {
    const void* poi  = d_in[0];
    const void* edge = d_in[1];
    const int* pte_rows = (const int*)d_in[2];
    const int* pte_cols = (const int*)d_in[3];
    const void* pte_vals = d_in[4];
    const int* etp_rows = (const int*)d_in[5];
    const int* etp_cols = (const int*)d_in[6];
    const void* etp_vals = d_in[7];
    const void* Wp = d_in[8];
    const void* We = d_in[9];
    const void* Wf = d_in[10];

    int n_poi  = in_sizes[0] / EMB;   // 100000
    int n_edge = in_sizes[1] / EMB;   // 50000
    int nnz1 = in_sizes[2];           // 3.2M (pte)
    int nnz2 = in_sizes[5];           // 3.2M (etp)

    // workspace (~14.8 MB)
    char* ws = (char*)d_ws;
    size_t off = 0;
    auto alloc = [&](size_t bytes) -> char* {
        char* p = ws + off;
        off = (off + bytes + 255) & ~(size_t)255;
        return p;
    };
    int* flag = (int*)alloc(4);
    int* pte_cnt = (int*)alloc((size_t)n_edge * 4);
    int* pte_cur = (int*)alloc((size_t)n_edge * 4);
    int* pte_ptr = (int*)alloc(((size_t)n_edge + 1) * 4);
    int* etp_cnt = (int*)alloc((size_t)n_poi * 4);
    int* etp_cur = (int*)alloc((size_t)n_poi * 4);
    int* etp_ptr = (int*)alloc(((size_t)n_poi + 1) * 4);
    int* bsum = (int*)alloc(128 * 4);
    int* bptr = (int*)alloc(129 * 4);
    int* bcur = (int*)alloc(128 * 4);
    int nnz_max = (nnz1 > nnz2) ? nnz1 : nnz2;
    unsigned int* ent = (unsigned int*)alloc((size_t)nnz_max * 4);   // shared, reused
    unsigned short* wc = (unsigned short*)alloc((size_t)2 * EMB * EMB * 2);

    // poi_agg (always bf16) parks at d_out base; consumed by k_fused before spmm#2 overwrites.
    unsigned short* poi_agg = (unsigned short*)d_out;
    size_t fused_off = (size_t)n_poi * EMB;   // element offset of output 1 in d_out

    k_probe<<<1, 256, 0, stream>>>((const unsigned int*)poi, flag);

    hipMemsetAsync(pte_cnt, 0, (size_t)n_edge * 4, stream);
    hipMemsetAsync(etp_cnt, 0, (size_t)n_poi * 4, stream);

    k_hist<<<2048, 256, 0, stream>>>(pte_rows, nnz1, pte_cnt);
    k_hist<<<2048, 256, 0, stream>>>(etp_rows, nnz2, etp_cnt);

    int nb1 = (n_edge + 1023) / 1024;   // 49
    int nb2 = (n_poi + 1023) / 1024;    // 98
    k_reduce<<<nb1, 1024, 0, stream>>>(pte_cnt, n_edge, bsum);
    k_scan<<<1, 1024, 0, stream>>>(bsum, nb1, bptr, bcur);
    k_scan_apply<<<nb1, 1024, 0, stream>>>(pte_cnt, n_edge, bptr, pte_ptr, pte_cur, nb1);
    k_reduce<<<nb2, 1024, 0, stream>>>(etp_cnt, n_poi, bsum);
    k_scan<<<1, 1024, 0, stream>>>(bsum, nb2, bptr, bcur);
    k_scan_apply<<<nb2, 1024, 0, stream>>>(etp_cnt, n_poi, bptr, etp_ptr, etp_cur, nb2);

    k_wprep<<<256, 128, 0, stream>>>(Wp, We, Wf, flag, wc);

    // spmm#1: poi_agg[e] = sum vals * poi_embs[col]  (W folded into fused GEMM)
    k_scatter<<<2048, 256, 0, stream>>>(pte_rows, pte_cols, pte_vals, nnz1, flag, pte_cur, ent);
    k_spmm<<<(n_edge + 3) / 4, 256, 0, stream>>>(pte_ptr, ent, poi, 0, poi_agg, n_edge, flag, 0);
    // fused_edge = poi_agg @ (Wp@Wf_top) + edge @ (We@Wf_bot) -> d_out[fused_off..]
    k_fused<<<(n_edge + 1) / 2, 128, 0, stream>>>(poi_agg, edge, d_out, fused_off, n_edge, flag, wc);
    // spmm#2: propagated_poi = spmm(etp, fused_edge) -> d_out[0..]
    k_scatter<<<2048, 256, 0, stream>>>(etp_rows, etp_cols, etp_vals, nnz2, flag, etp_cur, ent);
    k_spmm<<<(n_poi + 3) / 4, 256, 0, stream>>>(etp_ptr, ent, d_out, fused_off, d_out, n_poi, flag, 1);
}

// Round 4
// 1309.199 us; speedup vs baseline: 1.3580x; 1.3580x over previous
//
#include <hip/hip_runtime.h>

#define EMB 128

typedef float v4f __attribute__((ext_vector_type(4)));
typedef short v8s __attribute__((ext_vector_type(8)));

__device__ inline float bf_lo(unsigned int u) { return __builtin_bit_cast(float, u << 16); }
__device__ inline float bf_hi(unsigned int u) { return __builtin_bit_cast(float, u & 0xffff0000u); }
__device__ inline unsigned short f2bf(float x) {
    unsigned int u = __builtin_bit_cast(unsigned int, x);
    return (unsigned short)((u + 0x7fffu + ((u >> 16) & 1u)) >> 16);   // RNE
}

// ---------------- CSR build ----------------

__global__ void k_hist(const int* __restrict__ rows, int n, int* __restrict__ cnt) {
    for (int i = blockIdx.x * blockDim.x + threadIdx.x; i < n; i += gridDim.x * blockDim.x)
        atomicAdd(&cnt[rows[i]], 1);
}

__global__ __launch_bounds__(1024) void k_reduce(const int* __restrict__ cnt, int n,
                                                 int* __restrict__ bsum) {
    __shared__ int wsum[16];
    int tid = threadIdx.x;
    int idx = blockIdx.x * 1024 + tid;
    int v = (idx < n) ? cnt[idx] : 0;
    #pragma unroll
    for (int off = 32; off >= 1; off >>= 1) v += __shfl_down(v, off);
    if ((tid & 63) == 0) wsum[tid >> 6] = v;
    __syncthreads();
    if (tid == 0) {
        int s = 0;
        #pragma unroll
        for (int w = 0; w < 16; ++w) s += wsum[w];
        bsum[blockIdx.x] = s;
    }
}

__global__ __launch_bounds__(1024) void k_scan(const int* __restrict__ cnt, int n,
                                               int* __restrict__ ptr) {
    __shared__ int wsum[16];
    __shared__ int wpre[16];
    __shared__ int s_carry;
    int tid = threadIdx.x, lane = tid & 63, wid = tid >> 6;
    if (tid == 0) s_carry = 0;
    __syncthreads();
    for (int base = 0; base < n; base += 1024) {
        int idx = base + tid;
        int v = (idx < n) ? cnt[idx] : 0;
        int incl = v;
        #pragma unroll
        for (int off = 1; off < 64; off <<= 1) {
            int t = __shfl_up(incl, off);
            if (lane >= off) incl += t;
        }
        if (lane == 63) wsum[wid] = incl;
        __syncthreads();
        if (tid == 0) {
            int run = s_carry;
            #pragma unroll
            for (int w = 0; w < 16; ++w) { wpre[w] = run; run += wsum[w]; }
            s_carry = run;
        }
        __syncthreads();
        int excl = wpre[wid] + incl - v;
        if (idx < n) ptr[idx] = excl;
        __syncthreads();
    }
    if (tid == 0) ptr[n] = s_carry;
}

__global__ __launch_bounds__(1024) void k_scan_apply(const int* __restrict__ cnt, int n,
                                                     const int* __restrict__ bpre,
                                                     int* __restrict__ ptr, int* __restrict__ cur,
                                                     int nb) {
    __shared__ int wsum[16];
    __shared__ int wpre[16];
    int tid = threadIdx.x, lane = tid & 63, wid = tid >> 6;
    int idx = blockIdx.x * 1024 + tid;
    int v = (idx < n) ? cnt[idx] : 0;
    int incl = v;
    #pragma unroll
    for (int off = 1; off < 64; off <<= 1) {
        int t = __shfl_up(incl, off);
        if (lane >= off) incl += t;
    }
    if (lane == 63) wsum[wid] = incl;
    __syncthreads();
    if (tid == 0) {
        int run = bpre[blockIdx.x];
        #pragma unroll
        for (int w = 0; w < 16; ++w) { wpre[w] = run; run += wsum[w]; }
    }
    __syncthreads();
    int excl = wpre[wid] + incl - v;
    if (idx < n) { ptr[idx] = excl; cur[idx] = excl; }
    if (idx == 0) ptr[n] = bpre[nb];
}

// entry = (col << 15) | (bf16 bits of val; sign=0 since vals in [0,1))
__global__ void k_scatter(const int* __restrict__ rows, const int* __restrict__ cols,
                          const float* __restrict__ vals, int n,
                          int* __restrict__ cur, unsigned int* __restrict__ ent) {
    for (int i = blockIdx.x * blockDim.x + threadIdx.x; i < n; i += gridDim.x * blockDim.x) {
        int r = rows[i];
        int p = atomicAdd(&cur[r], 1);
        ent[p] = ((unsigned int)cols[i] << 15) | (unsigned int)f2bf(vals[i]);
    }
}

// ---------------- fp32 -> bf16 table conversion ----------------
__global__ __launch_bounds__(256) void k_cvt(const float* __restrict__ src,
                                             unsigned short* __restrict__ dst, int n4) {
    int i = blockIdx.x * blockDim.x + threadIdx.x;
    if (i >= n4) return;
    v4f f = *(const v4f*)(src + (size_t)i * 4);
    ushort4 o;
    o.x = f2bf(f.x); o.y = f2bf(f.y); o.z = f2bf(f.z); o.w = f2bf(f.w);
    *(ushort4*)(dst + (size_t)i * 4) = o;
}

// ---------------- SpMM: one wave per row; bf16 table; lane covers cols 2l,2l+1 ----------------
__global__ __launch_bounds__(256) void k_spmm(const int* __restrict__ ptr,
                                              const unsigned int* __restrict__ ent,
                                              const unsigned short* __restrict__ table,
                                              void* __restrict__ out, int nrows, int out_fp32) {
    int lane = threadIdx.x & 63;
    int row = (blockIdx.x << 2) + (threadIdx.x >> 6);
    if (row >= nrows) return;
    int beg = ptr[row], end = ptr[row + 1];
    float a0 = 0.f, a1 = 0.f;
    for (int i = beg; i < end; i += 64) {
        int nb = min(64, end - i);
        unsigned int e = 0u;
        if (lane < nb) e = ent[i + lane];
        #pragma unroll 4
        for (int j = 0; j < nb; ++j) {
            unsigned int ee = (unsigned int)__shfl((int)e, j);
            int c = (int)(ee >> 15);
            float v = __builtin_bit_cast(float, (ee & 0x7FFFu) << 16);
            unsigned int u = *(const unsigned int*)(table + ((size_t)c << 7) + (lane << 1));
            a0 = fmaf(v, bf_lo(u), a0);
            a1 = fmaf(v, bf_hi(u), a1);
        }
    }
    if (out_fp32) {
        float* po = (float*)out + ((size_t)row << 7) + (lane << 1);
        po[0] = a0;
        po[1] = a1;
    } else {
        unsigned int o = (unsigned int)f2bf(a0) | ((unsigned int)f2bf(a1) << 16);
        *(unsigned int*)((unsigned short*)out + ((size_t)row << 7) + (lane << 1)) = o;
    }
}

// ---------------- weight prep (fp32 in): Wc = [Wp@Wf_top ; We@Wf_bot], B-fragment packed ----------------
// element (k,n) -> wc[((k>>3)*128 + n)*8 + (k&7)]
__global__ __launch_bounds__(128) void k_wprep(const float* __restrict__ Wp,
                                               const float* __restrict__ We,
                                               const float* __restrict__ Wf,
                                               unsigned short* __restrict__ wc) {
    int k = blockIdx.x;    // 0..255
    int n = threadIdx.x;   // 0..127
    const float* wrow = (k < 128) ? (Wp + (size_t)k * EMB) : (We + (size_t)(k - 128) * EMB);
    const float* wf = Wf + (size_t)k * EMB + n;   // Wf row index == k (0..255)
    float acc = 0.f;
    #pragma unroll 4
    for (int j = 0; j < EMB; ++j)
        acc = fmaf(wrow[j], Wf[(size_t)((k < 128) ? j : (128 + j)) * EMB + n], acc);
    (void)wf;
    wc[(((k >> 3) * EMB) + n) * 8 + (k & 7)] = f2bf(acc);
}

// ---------------- fused GEMM (MFMA 16x16x32 bf16): M=nrows, K=256, N=128 ----------------
// A: k<128 from poi_agg (bf16), k>=128 from edge (fp32, cvt in-register). Dual-write fp32+bf16.
__global__ __launch_bounds__(256) void k_fused(const unsigned short* __restrict__ poi_agg,
                                               const float* __restrict__ edge,
                                               const unsigned short* __restrict__ wc,
                                               float* __restrict__ fused32,
                                               unsigned short* __restrict__ fused16, int nrows) {
    __shared__ __align__(16) unsigned short lds_w[32768];   // 64 KB packed B
    {
        const uint4* s = (const uint4*)wc;
        uint4* d = (uint4*)lds_w;
        #pragma unroll
        for (int i = 0; i < 16; ++i) d[threadIdx.x + i * 256] = s[threadIdx.x + i * 256];
    }
    __syncthreads();
    int lane = threadIdx.x & 63;
    int row_base = blockIdx.x * 64 + (threadIdx.x >> 6) * 16;
    int m = lane & 15, kq = lane >> 4;
    int arow = row_base + m;
    if (arow >= nrows) arow = nrows - 1;              // clamp reads; writes guarded
    const unsigned short* ap_p = poi_agg + (size_t)arow * EMB;
    const float* ap_e = edge + (size_t)arow * EMB;
    v4f zero = {0.f, 0.f, 0.f, 0.f};
    v4f acc[8];
    #pragma unroll
    for (int t = 0; t < 8; ++t) acc[t] = zero;
    #pragma unroll
    for (int kt = 0; kt < 8; ++kt) {
        v8s a;
        if (kt < 4) {
            a = *(const v8s*)(ap_p + kt * 32 + kq * 8);          // bf16 direct
        } else {
            int k0 = (kt - 4) * 32 + kq * 8;
            v4f f0 = *(const v4f*)(ap_e + k0);
            v4f f1 = *(const v4f*)(ap_e + k0 + 4);
            a[0] = (short)f2bf(f0.x); a[1] = (short)f2bf(f0.y);
            a[2] = (short)f2bf(f0.z); a[3] = (short)f2bf(f0.w);
            a[4] = (short)f2bf(f1.x); a[5] = (short)f2bf(f1.y);
            a[6] = (short)f2bf(f1.z); a[7] = (short)f2bf(f1.w);
        }
        int kk = kt * 4 + kq;                                    // k-octet index
        #pragma unroll
        for (int nt = 0; nt < 8; ++nt) {
            v8s b = *(const v8s*)(lds_w + ((kk * EMB + nt * 16 + m) << 3));
            acc[nt] = __builtin_amdgcn_mfma_f32_16x16x32_bf16(a, b, acc[nt], 0, 0, 0);
        }
    }
    // C/D: col = lane&15, row = (lane>>4)*4 + r   [m89/m91-verified]
    #pragma unroll
    for (int r = 0; r < 4; ++r) {
        int ro = row_base + kq * 4 + r;
        if (ro >= nrows) continue;
        #pragma unroll
        for (int nt = 0; nt < 8; ++nt) {
            float x = acc[nt][r];
            size_t o = (size_t)ro * EMB + nt * 16 + m;
            fused32[o] = x;
            fused16[o] = f2bf(x);
        }
    }
}

extern "C" void kernel_launch(void* const* d_in, const int* in_sizes, int n_in,
                              void* d_out, int out_size, void* d_ws, size_t ws_size,
                              hipStream_t stream) {
    const float* poi  = (const float*)d_in[0];
    const float* edge = (const float*)d_in[1];
    const int* pte_rows = (const int*)d_in[2];
    const int* pte_cols = (const int*)d_in[3];
    const float* pte_vals = (const float*)d_in[4];
    const int* etp_rows = (const int*)d_in[5];
    const int* etp_cols = (const int*)d_in[6];
    const float* etp_vals = (const float*)d_in[7];
    const float* Wp = (const float*)d_in[8];
    const float* We = (const float*)d_in[9];
    const float* Wf = (const float*)d_in[10];

    int n_poi  = in_sizes[0] / EMB;   // 100000
    int n_edge = in_sizes[1] / EMB;   // 50000
    int nnz1 = in_sizes[2];           // 3.2M (pte)
    int nnz2 = in_sizes[5];           // 3.2M (etp)

    // ---- workspace (~27 MB) ----
    char* ws = (char*)d_ws;
    size_t off = 0;
    auto alloc = [&](size_t bytes) -> char* {
        char* p = ws + off;
        off = (off + bytes + 255) & ~(size_t)255;
        return p;
    };
    int* pte_cnt = (int*)alloc((size_t)n_edge * 4);
    int* pte_cur = (int*)alloc((size_t)n_edge * 4);
    int* pte_ptr = (int*)alloc(((size_t)n_edge + 1) * 4);
    int* etp_cnt = (int*)alloc((size_t)n_poi * 4);
    int* etp_cur = (int*)alloc((size_t)n_poi * 4);
    int* etp_ptr = (int*)alloc(((size_t)n_poi + 1) * 4);
    int* bsum = (int*)alloc(128 * 4);
    int* bptr = (int*)alloc(129 * 4);
    int nnz_max = (nnz1 > nnz2) ? nnz1 : nnz2;
    unsigned int* ent = (unsigned int*)alloc((size_t)nnz_max * 4);         // reused pte -> etp
    unsigned short* wc = (unsigned short*)alloc((size_t)2 * EMB * EMB * 2);
    unsigned short* fused16 = (unsigned short*)alloc((size_t)n_edge * EMB * 2);

    // ---- d_out parking (output-0 region is 51.2 MB fp32, written LAST by spmm#2) ----
    float* out_prop = (float*)d_out;                                  // [n_poi][128] fp32
    float* out_fused = out_prop + (size_t)n_poi * EMB;                // [n_edge][128] fp32
    unsigned short* poi_agg = (unsigned short*)d_out;                 // 12.8 MB bf16
    unsigned short* poi_bf = (unsigned short*)((char*)d_out + (size_t)n_edge * EMB * 2);  // 25.6 MB bf16

    hipMemsetAsync(pte_cnt, 0, (size_t)n_edge * 4, stream);
    hipMemsetAsync(etp_cnt, 0, (size_t)n_poi * 4, stream);

    k_hist<<<2048, 256, 0, stream>>>(pte_rows, nnz1, pte_cnt);
    k_hist<<<2048, 256, 0, stream>>>(etp_rows, nnz2, etp_cnt);

    int nb1 = (n_edge + 1023) / 1024;   // 49
    int nb2 = (n_poi + 1023) / 1024;    // 98
    k_reduce<<<nb1, 1024, 0, stream>>>(pte_cnt, n_edge, bsum);
    k_scan<<<1, 1024, 0, stream>>>(bsum, nb1, bptr);
    k_scan_apply<<<nb1, 1024, 0, stream>>>(pte_cnt, n_edge, bptr, pte_ptr, pte_cur, nb1);
    k_reduce<<<nb2, 1024, 0, stream>>>(etp_cnt, n_poi, bsum);
    k_scan<<<1, 1024, 0, stream>>>(bsum, nb2, bptr);
    k_scan_apply<<<nb2, 1024, 0, stream>>>(etp_cnt, n_poi, bptr, etp_ptr, etp_cur, nb2);

    k_wprep<<<256, 128, 0, stream>>>(Wp, We, Wf, wc);
    k_cvt<<<(n_poi * EMB / 4 + 255) / 256, 256, 0, stream>>>(poi, poi_bf, n_poi * EMB / 4);

    // spmm#1: poi_agg[e] = sum vals * poi[col]  (weights folded into fused GEMM)
    k_scatter<<<2048, 256, 0, stream>>>(pte_rows, pte_cols, pte_vals, nnz1, pte_cur, ent);
    k_spmm<<<(n_edge + 3) / 4, 256, 0, stream>>>(pte_ptr, ent, poi_bf, poi_agg, n_edge, 0);
    // fused = poi_agg @ (Wp@Wf_top) + edge @ (We@Wf_bot); dual-write fp32 (out) + bf16 (gather table)
    k_fused<<<(n_edge + 63) / 64, 256, 0, stream>>>(poi_agg, edge, wc, out_fused, fused16, n_edge);
    // spmm#2: propagated_poi = spmm(etp, fused) -> output 0 (overwrites parked poi_agg/poi_bf)
    k_scatter<<<2048, 256, 0, stream>>>(etp_rows, etp_cols, etp_vals, nnz2, etp_cur, ent);
    k_spmm<<<(n_poi + 3) / 4, 256, 0, stream>>>(etp_ptr, ent, fused16, out_prop, n_poi, 1);
}